// Round 3
// baseline (362.625 us; speedup 1.0000x reference)
//
#include <hip/hip_runtime.h>
#include <math.h>

#define B_SZ 16
#define D_CH 512
#define U_LEN 2048
#define R_LEN 512
#define T_LEN 2560
#define KS 31
#define CS 30

typedef __attribute__((ext_vector_type(8))) short short8;
typedef __attribute__((ext_vector_type(4))) float floatx4;

__device__ __forceinline__ float bf2f(ushort u) {
    unsigned v = (unsigned)u << 16;
    float f; __builtin_memcpy(&f, &v, 4); return f;
}
__device__ __forceinline__ ushort f2bf(float f) {
    unsigned v; __builtin_memcpy(&v, &f, 4);
    v += 0x7fff + ((v >> 16) & 1);
    return (ushort)(v >> 16);
}
__device__ __forceinline__ float sigmoidf_(float x) { return 1.0f / (1.0f + __expf(-x)); }

__device__ __forceinline__ void gld16(const void* g, void* l) {
    __builtin_amdgcn_global_load_lds((const __attribute__((address_space(1))) void*)g,
                                     (__attribute__((address_space(3))) void*)l, 16, 0, 0);
}

// ---- conversion kernel ----
// xb (T,B,D) bf16; w1b bf16 16-row a/g interleaved; w2b bf16; pu rows P<30 <- input cache
// (pu = padded-utterance buffer, 2078 frames x 16 b x 512 d, frames >=30 written by k1);
// wdT[k][d] fp32 transposed depthwise weights (coalesced loads in k2).
__global__ __launch_bounds__(256) void k_conv_all(
    const float* __restrict__ utt, const float* __restrict__ rc, const float* __restrict__ cache,
    const float* __restrict__ w1, const float* __restrict__ w2, const float* __restrict__ wd,
    ushort* __restrict__ xb, ushort* __restrict__ w1b, ushort* __restrict__ w2b,
    ushort* __restrict__ pu, float* __restrict__ wdT)
{
    int blk = blockIdx.x;
    if (blk < 5120) {
        size_t f4 = (size_t)blk * 1024 + threadIdx.x * 4;
        size_t o = f4 * 4;
        int q = (int)(o >> 9), d = (int)(o & 511);
        const float* src = (q < 8192) ? rc + ((size_t)q << 9) + d
                                      : utt + (((size_t)(q - 8192)) << 9) + d;
        ushort* dst = xb + o;
        #pragma unroll
        for (int i = 0; i < 4; ++i) {
            float4 v = ((const float4*)src)[i];
            ushort4 u4; u4.x = f2bf(v.x); u4.y = f2bf(v.y); u4.z = f2bf(v.z); u4.w = f2bf(v.w);
            ((ushort4*)dst)[i] = u4;
        }
    } else if (blk < 5312) {
        int t = (blk - 5120) * 1024 + threadIdx.x * 4;
        if (t < 131072) {
            // w1 with 16-row a/g interleave
            #pragma unroll
            for (int i = 0; i < 4; ++i) {
                int e = (t + i) << 2;           // element index into [1024][512]
                int row = e >> 9, k = e & 511;
                int rr = row & 511;
                int rp = (rr >> 4) * 32 + ((row >> 9) << 4) + (rr & 15);
                float4 v = ((const float4*)w1)[t + i];
                ushort4 u4; u4.x = f2bf(v.x); u4.y = f2bf(v.y); u4.z = f2bf(v.z); u4.w = f2bf(v.w);
                ((ushort4*)w1b)[rp * 128 + (k >> 2)] = u4;
            }
        } else {
            int t2 = t - 131072;
            #pragma unroll
            for (int i = 0; i < 4; ++i) {
                float4 v = ((const float4*)w2)[t2 + i];
                ushort4 u4; u4.x = f2bf(v.x); u4.y = f2bf(v.y); u4.z = f2bf(v.z); u4.w = f2bf(v.w);
                ((ushort4*)w2b)[t2 + i] = u4;
            }
        }
    } else if (blk < 6272) {
        int o = (blk - 5312) * 256 + threadIdx.x;     // < 245760
        int d = o & 511, p = o >> 13, b = (o >> 9) & 15;
        pu[o] = f2bf(cache[((size_t)b * D_CH + d) * CS + p]);
    } else {
        int idx = (blk - 6272) * 256 + threadIdx.x;   // < 15872
        int k = idx >> 9, d = idx & 511;
        wdT[idx] = wd[(size_t)d * KS + k];
    }
}

// ---- K1: depth-3 counted-vmcnt pipelined MFMA GEMM (xb @ w1p^T) + GLU ----
// rc rows (q<8192) -> yr; utt rows -> pu at row q-7712 (frame P = t-482).
__global__ __launch_bounds__(256, 2) void k1_mfma(
    const ushort* __restrict__ xb, const ushort* __restrict__ w1p,
    const float* __restrict__ b1, ushort* __restrict__ yr, ushort* __restrict__ pu)
{
    __shared__ __attribute__((aligned(16))) ushort lds[4][2][4096];
    const int tid = threadIdx.x;
    const int w = tid >> 6, lane = tid & 63;
    const int col = lane & 15, quad = lane >> 4;
    const int wm = w >> 1, wn = w & 1;
    const int bid = blockIdx.x;
    const int f = (bid & 7) * 320 + (bid >> 3);
    const int mt = f >> 3, nn = f & 7;
    const int q0 = mt * 128, n0 = nn * 128;

    floatx4 acc[4][4];
    #pragma unroll
    for (int i = 0; i < 4; ++i)
        #pragma unroll
        for (int j = 0; j < 4; ++j) acc[i][j] = 0.f;

    int offA[4], offB[4];
    #pragma unroll
    for (int i = 0; i < 4; ++i) {
        int rA = wm * 64 + i * 16 + col;
        offA[i] = rA * 64 + ((quad ^ ((rA >> 1) & 3)) << 4);
        int rB = wn * 64 + i * 16 + col;
        offB[i] = rB * 64 + ((quad ^ ((rB >> 1) & 3)) << 4);
    }

    const int srow = tid >> 2;
    const int sqs = (tid & 3) ^ ((srow >> 1) & 3);
    const ushort* gA0 = xb  + (((size_t)(q0 + srow))      << 9) + (sqs << 3);
    const ushort* gA1 = xb  + (((size_t)(q0 + 64 + srow)) << 9) + (sqs << 3);
    const ushort* gB0 = w1p + (((size_t)(n0 + srow))      << 9) + (sqs << 3);
    const ushort* gB1 = w1p + (((size_t)(n0 + 64 + srow)) << 9) + (sqs << 3);

#define STAGE1(t_, bi_) do { \
        const int kc_ = (t_) << 5; \
        gld16(gA0 + kc_, &lds[bi_][0][w * 512]); \
        gld16(gA1 + kc_, &lds[bi_][0][2048 + w * 512]); \
        gld16(gB0 + kc_, &lds[bi_][1][w * 512]); \
        gld16(gB1 + kc_, &lds[bi_][1][2048 + w * 512]); \
    } while (0)

    STAGE1(0, 0); STAGE1(1, 1); STAGE1(2, 2);

    #pragma unroll
    for (int s = 0; s < 16; ++s) {
        if (s < 14)       asm volatile("s_waitcnt vmcnt(8)\n\ts_barrier" ::: "memory");
        else if (s == 14) asm volatile("s_waitcnt vmcnt(4)\n\ts_barrier" ::: "memory");
        else              asm volatile("s_waitcnt vmcnt(0)\n\ts_barrier" ::: "memory");
        if (s < 13) STAGE1(s + 3, (s + 3) & 3);
        const char* A  = (const char*)&lds[s & 3][0][0];
        const char* Bp = (const char*)&lds[s & 3][1][0];
        short8 af[4], bf8[4];
        #pragma unroll
        for (int i = 0; i < 4; ++i) af[i]  = *(const short8*)(A + offA[i]);
        #pragma unroll
        for (int j = 0; j < 4; ++j) bf8[j] = *(const short8*)(Bp + offB[j]);
        __builtin_amdgcn_s_setprio(1);
        #pragma unroll
        for (int i = 0; i < 4; ++i)
            #pragma unroll
            for (int j = 0; j < 4; ++j)
                acc[i][j] = __builtin_amdgcn_mfma_f32_16x16x32_bf16(af[i], bf8[j], acc[i][j], 0, 0, 0);
        __builtin_amdgcn_s_setprio(0);
    }
#undef STAGE1

    // GLU epilogue: fc even = a, fc odd = g (same output col n, same lane)
    ushort* dst = (q0 < 8192) ? yr : pu;
    const int qb = (q0 < 8192) ? q0 : (q0 - 7712);
    const int nb2 = (n0 + wn * 64) >> 1;
    #pragma unroll
    for (int fe = 0; fe < 2; ++fe) {
        const int na = nb2 + fe * 16 + col;
        const float ba = b1[na], bg = b1[512 + na];
        #pragma unroll
        for (int i = 0; i < 4; ++i) {
            const int row = qb + wm * 64 + i * 16 + quad * 4;
            #pragma unroll
            for (int r = 0; r < 4; ++r) {
                float a = acc[i][2 * fe][r] + ba;
                float g = acc[i][2 * fe + 1][r] + bg;
                dst[(((size_t)(row + r)) << 9) + na] = f2bf(a * sigmoidf_(g));
            }
        }
    }
}

// ---- K2: LDS-free streaming depthwise conv + swish -> zb; emits new_cache ----
// utt path: thread = (b,d), 32 outputs, 62 coalesced bf16 taps from pu (no branch:
// cache frames pre-merged into pu rows P<30). rc path: 38 taps (30 pu + 8 yr).
// Weights from wdT (coalesced), held in 31 VGPRs. No LDS, no barriers.
__global__ __launch_bounds__(256) void k2_fused(
    const ushort* __restrict__ pu, const ushort* __restrict__ yr,
    const float* __restrict__ wdT, const float* __restrict__ bd,
    ushort* __restrict__ z, float* __restrict__ out)
{
    const int tid = threadIdx.x;
    const int bid = blockIdx.x;
    if (bid < 2048) {
        const int ug = bid & 63, b = (bid >> 6) & 15, dh = bid >> 10;
        const int d = dh * 256 + tid;
        const int u0 = ug * 32;
        float wreg[31];
        #pragma unroll
        for (int k = 0; k < 31; ++k) wreg[k] = wdT[k * 512 + d];
        const float bias = bd[d];
        float acc[32];
        #pragma unroll
        for (int i = 0; i < 32; ++i) acc[i] = bias;
        const ushort* base = pu + (((size_t)u0 * 16 + b) << 9) + d;
        #pragma unroll
        for (int p = 0; p < 62; ++p) {
            float v = bf2f(base[(size_t)p * 8192]);
            #pragma unroll
            for (int i = 0; i < 32; ++i) {
                int k = p - i;
                if (k >= 0 && k < 31) acc[i] = fmaf(wreg[k], v, acc[i]);
            }
        }
        ushort* zp = z + d;
        #pragma unroll
        for (int i = 0; i < 32; ++i) {
            float v = acc[i];
            v = v * sigmoidf_(v - 1.0f);
            zp[((size_t)((R_LEN + u0 + i) * 16 + b)) << 9] = f2bf(v);
        }
        // new_cache: pad frames 2048..2077 = taps p=32..61 of the last u-group
        if (ug == 63) {
            float* outc = out + 20971520 + ((size_t)b * 512 + d) * 30;
            #pragma unroll
            for (int p = 32; p < 62; ++p)
                outc[p - 32] = bf2f(base[(size_t)p * 8192]);
        }
    } else {
        const int m = bid - 2048;
        const int ci = m & 63, b = (m >> 6) & 15, dh = m >> 10;
        const int d = dh * 256 + tid;
        float wreg[31];
        #pragma unroll
        for (int k = 0; k < 31; ++k) wreg[k] = wdT[k * 512 + d];
        const float bias = bd[d];
        float acc[8];
        #pragma unroll
        for (int j = 0; j < 8; ++j) acc[j] = bias;
        #pragma unroll
        for (int r = 0; r < 38; ++r) {
            const ushort* src = (r < 30)
                ? pu + (((size_t)((32 * ci + 32 + r) * 16 + b)) << 9) + d
                : yr + (((size_t)(((8 * ci) + (r - 30)) * 16 + b)) << 9) + d;
            float v = bf2f(*src);
            #pragma unroll
            for (int j = 0; j < 8; ++j) {
                int k = r - j;
                if (k >= 0 && k < 31) acc[j] = fmaf(wreg[k], v, acc[j]);
            }
        }
        #pragma unroll
        for (int j = 0; j < 8; ++j) {
            float v = acc[j];
            v = v * sigmoidf_(v - 1.0f);
            z[(((size_t)((ci * 8 + j) * 16 + b)) << 9) + d] = f2bf(v);
        }
    }
}

// ---- K3: depth-3 pipelined GEMM (zb @ w2b^T) + bias -> final fp32 ----
__global__ __launch_bounds__(256, 2) void k3_mfma(
    const ushort* __restrict__ zb, const ushort* __restrict__ w2b,
    const float* __restrict__ b2, float* __restrict__ out)
{
    __shared__ __attribute__((aligned(16))) ushort lds[4][2][4096];
    const int tid = threadIdx.x;
    const int w = tid >> 6, lane = tid & 63;
    const int col = lane & 15, quad = lane >> 4;
    const int wm = w >> 1, wn = w & 1;
    const int bid = blockIdx.x;
    const int f = (bid & 7) * 160 + (bid >> 3);
    const int mt = f >> 2, nn = f & 3;
    const int q0 = mt * 128, n0 = nn * 128;

    floatx4 acc[4][4];
    #pragma unroll
    for (int i = 0; i < 4; ++i)
        #pragma unroll
        for (int j = 0; j < 4; ++j) acc[i][j] = 0.f;

    int offA[4], offB[4];
    #pragma unroll
    for (int i = 0; i < 4; ++i) {
        int rA = wm * 64 + i * 16 + col;
        offA[i] = rA * 64 + ((quad ^ ((rA >> 1) & 3)) << 4);
        int rB = wn * 64 + i * 16 + col;
        offB[i] = rB * 64 + ((quad ^ ((rB >> 1) & 3)) << 4);
    }

    const int srow = tid >> 2;
    const int sqs = (tid & 3) ^ ((srow >> 1) & 3);
    const ushort* gA0 = zb  + (((size_t)(q0 + srow))      << 9) + (sqs << 3);
    const ushort* gA1 = zb  + (((size_t)(q0 + 64 + srow)) << 9) + (sqs << 3);
    const ushort* gB0 = w2b + (((size_t)(n0 + srow))      << 9) + (sqs << 3);
    const ushort* gB1 = w2b + (((size_t)(n0 + 64 + srow)) << 9) + (sqs << 3);

#define STAGE3(t_, bi_) do { \
        const int kc_ = (t_) << 5; \
        gld16(gA0 + kc_, &lds[bi_][0][w * 512]); \
        gld16(gA1 + kc_, &lds[bi_][0][2048 + w * 512]); \
        gld16(gB0 + kc_, &lds[bi_][1][w * 512]); \
        gld16(gB1 + kc_, &lds[bi_][1][2048 + w * 512]); \
    } while (0)

    STAGE3(0, 0); STAGE3(1, 1); STAGE3(2, 2);

    #pragma unroll
    for (int s = 0; s < 16; ++s) {
        if (s < 14)       asm volatile("s_waitcnt vmcnt(8)\n\ts_barrier" ::: "memory");
        else if (s == 14) asm volatile("s_waitcnt vmcnt(4)\n\ts_barrier" ::: "memory");
        else              asm volatile("s_waitcnt vmcnt(0)\n\ts_barrier" ::: "memory");
        if (s < 13) STAGE3(s + 3, (s + 3) & 3);
        const char* A  = (const char*)&lds[s & 3][0][0];
        const char* Bp = (const char*)&lds[s & 3][1][0];
        short8 af[4], bf8[4];
        #pragma unroll
        for (int i = 0; i < 4; ++i) af[i]  = *(const short8*)(A + offA[i]);
        #pragma unroll
        for (int j = 0; j < 4; ++j) bf8[j] = *(const short8*)(Bp + offB[j]);
        __builtin_amdgcn_s_setprio(1);
        #pragma unroll
        for (int i = 0; i < 4; ++i)
            #pragma unroll
            for (int j = 0; j < 4; ++j)
                acc[i][j] = __builtin_amdgcn_mfma_f32_16x16x32_bf16(af[i], bf8[j], acc[i][j], 0, 0, 0);
        __builtin_amdgcn_s_setprio(0);
    }
#undef STAGE3

    #pragma unroll
    for (int j = 0; j < 4; ++j) {
        const int n = n0 + wn * 64 + j * 16 + col;
        const float bb = b2[n];
        #pragma unroll
        for (int i = 0; i < 4; ++i) {
            const int qrow = q0 + wm * 64 + i * 16 + quad * 4;
            #pragma unroll
            for (int r = 0; r < 4; ++r) {
                const int q = qrow + r;
                float v = acc[i][j][r] + bb;
                size_t off = (q < 8192) ? (size_t)16777216 + ((size_t)q << 9)
                                        : ((size_t)(q - 8192) << 9);
                out[off + n] = v;
            }
        }
    }
}

extern "C" void kernel_launch(void* const* d_in, const int* in_sizes, int n_in,
                              void* d_out, int out_size, void* d_ws, size_t ws_size,
                              hipStream_t stream)
{
    const float* utt   = (const float*)d_in[0];
    const float* rc    = (const float*)d_in[1];
    const float* cache = (const float*)d_in[2];
    const float* w1    = (const float*)d_in[3];
    const float* b1    = (const float*)d_in[4];
    const float* wd    = (const float*)d_in[5];
    const float* bd    = (const float*)d_in[6];
    const float* w2    = (const float*)d_in[7];
    const float* b2    = (const float*)d_in[8];
    float* out = (float*)d_out;

    ushort* xb  = (ushort*)d_ws;                 // (T,B,D) bf16, rows q=t*16+b
    ushort* zb  = xb  + (size_t)20971520;        // k2 output / k3 input
    ushort* pu  = zb  + (size_t)20971520;        // padded utt: 2078 frames x 16 x 512 bf16
    ushort* yr  = pu  + (size_t)17039360;        // rc GLU rows: 512 frames x 16 x 512 bf16
    ushort* w1b = yr  + (size_t)4194304;         // w1 bf16, 16-row a/g interleaved
    ushort* w2b = w1b + (size_t)524288;
    float*  wdT = (float*)(w2b + (size_t)262144); // [31][512] fp32 transposed dw weights

    k_conv_all<<<dim3(6334), 256, 0, stream>>>(utt, rc, cache, w1, w2, wd, xb, w1b, w2b, pu, wdT);
    k1_mfma   <<<dim3(2560), 256, 0, stream>>>(xb, w1b, b1, yr, pu);
    k2_fused  <<<dim3(4096), 256, 0, stream>>>(pu, yr, wdT, bd, zb, out);
    k3_mfma   <<<dim3(1280), 256, 0, stream>>>(zb, w2b, b2, out);
}

// Round 4
// 294.796 us; speedup vs baseline: 1.2301x; 1.2301x over previous
//
#include <hip/hip_runtime.h>
#include <math.h>

#define B_SZ 16
#define D_CH 512
#define U_LEN 2048
#define R_LEN 512
#define T_LEN 2560
#define KS 31
#define CS 30

typedef __attribute__((ext_vector_type(8))) short short8;
typedef __attribute__((ext_vector_type(4))) float floatx4;

__device__ __forceinline__ float bf2f(ushort u) {
    unsigned v = (unsigned)u << 16;
    float f; __builtin_memcpy(&f, &v, 4); return f;
}
__device__ __forceinline__ ushort f2bf(float f) {
    unsigned v; __builtin_memcpy(&v, &f, 4);
    v += 0x7fff + ((v >> 16) & 1);
    return (ushort)(v >> 16);
}
__device__ __forceinline__ float sigmoidf_(float x) { return 1.0f / (1.0f + __expf(-x)); }

__device__ __forceinline__ void gld16(const void* g, void* l) {
    __builtin_amdgcn_global_load_lds((const __attribute__((address_space(1))) void*)g,
                                     (__attribute__((address_space(3))) void*)l, 16, 0, 0);
}

// ---- conversion kernel ----
// xb (T,B,D) bf16; w1b bf16 16-row a/g interleaved; w2b bf16; pu rows P<30 <- input cache
// (pu = padded-utterance buffer, 2078 frames x 16 b x 512 d, frames >=30 written by k1);
// wdT[k][d] fp32 transposed depthwise weights (coalesced loads in k2).
__global__ __launch_bounds__(256) void k_conv_all(
    const float* __restrict__ utt, const float* __restrict__ rc, const float* __restrict__ cache,
    const float* __restrict__ w1, const float* __restrict__ w2, const float* __restrict__ wd,
    ushort* __restrict__ xb, ushort* __restrict__ w1b, ushort* __restrict__ w2b,
    ushort* __restrict__ pu, float* __restrict__ wdT)
{
    int blk = blockIdx.x;
    if (blk < 5120) {
        size_t f4 = (size_t)blk * 1024 + threadIdx.x * 4;
        size_t o = f4 * 4;
        int q = (int)(o >> 9), d = (int)(o & 511);
        const float* src = (q < 8192) ? rc + ((size_t)q << 9) + d
                                      : utt + (((size_t)(q - 8192)) << 9) + d;
        ushort* dst = xb + o;
        #pragma unroll
        for (int i = 0; i < 4; ++i) {
            float4 v = ((const float4*)src)[i];
            ushort4 u4; u4.x = f2bf(v.x); u4.y = f2bf(v.y); u4.z = f2bf(v.z); u4.w = f2bf(v.w);
            ((ushort4*)dst)[i] = u4;
        }
    } else if (blk < 5312) {
        int t = (blk - 5120) * 1024 + threadIdx.x * 4;
        if (t < 131072) {
            // w1 with 16-row a/g interleave
            #pragma unroll
            for (int i = 0; i < 4; ++i) {
                int e = (t + i) << 2;           // element index into [1024][512]
                int row = e >> 9, k = e & 511;
                int rr = row & 511;
                int rp = (rr >> 4) * 32 + ((row >> 9) << 4) + (rr & 15);
                float4 v = ((const float4*)w1)[t + i];
                ushort4 u4; u4.x = f2bf(v.x); u4.y = f2bf(v.y); u4.z = f2bf(v.z); u4.w = f2bf(v.w);
                ((ushort4*)w1b)[rp * 128 + (k >> 2)] = u4;
            }
        } else {
            int t2 = t - 131072;
            #pragma unroll
            for (int i = 0; i < 4; ++i) {
                float4 v = ((const float4*)w2)[t2 + i];
                ushort4 u4; u4.x = f2bf(v.x); u4.y = f2bf(v.y); u4.z = f2bf(v.z); u4.w = f2bf(v.w);
                ((ushort4*)w2b)[t2 + i] = u4;
            }
        }
    } else if (blk < 6272) {
        int o = (blk - 5312) * 256 + threadIdx.x;     // < 245760
        int d = o & 511, p = o >> 13, b = (o >> 9) & 15;
        pu[o] = f2bf(cache[((size_t)b * D_CH + d) * CS + p]);
    } else {
        int idx = (blk - 6272) * 256 + threadIdx.x;   // < 15872
        int k = idx >> 9, d = idx & 511;
        wdT[idx] = wd[(size_t)d * KS + k];
    }
}

// ---- K1: depth-3 counted-vmcnt pipelined MFMA GEMM (xb @ w1p^T) + GLU ----
// rc rows (q<8192) -> yr; utt rows -> pu at row q-7712 (frame P = t-482).
__global__ __launch_bounds__(256, 2) void k1_mfma(
    const ushort* __restrict__ xb, const ushort* __restrict__ w1p,
    const float* __restrict__ b1, ushort* __restrict__ yr, ushort* __restrict__ pu)
{
    __shared__ __attribute__((aligned(16))) ushort lds[4][2][4096];
    const int tid = threadIdx.x;
    const int w = tid >> 6, lane = tid & 63;
    const int col = lane & 15, quad = lane >> 4;
    const int wm = w >> 1, wn = w & 1;
    const int bid = blockIdx.x;
    const int f = (bid & 7) * 320 + (bid >> 3);
    const int mt = f >> 3, nn = f & 7;
    const int q0 = mt * 128, n0 = nn * 128;

    floatx4 acc[4][4];
    #pragma unroll
    for (int i = 0; i < 4; ++i)
        #pragma unroll
        for (int j = 0; j < 4; ++j) acc[i][j] = 0.f;

    int offA[4], offB[4];
    #pragma unroll
    for (int i = 0; i < 4; ++i) {
        int rA = wm * 64 + i * 16 + col;
        offA[i] = rA * 64 + ((quad ^ ((rA >> 1) & 3)) << 4);
        int rB = wn * 64 + i * 16 + col;
        offB[i] = rB * 64 + ((quad ^ ((rB >> 1) & 3)) << 4);
    }

    const int srow = tid >> 2;
    const int sqs = (tid & 3) ^ ((srow >> 1) & 3);
    const ushort* gA0 = xb  + (((size_t)(q0 + srow))      << 9) + (sqs << 3);
    const ushort* gA1 = xb  + (((size_t)(q0 + 64 + srow)) << 9) + (sqs << 3);
    const ushort* gB0 = w1p + (((size_t)(n0 + srow))      << 9) + (sqs << 3);
    const ushort* gB1 = w1p + (((size_t)(n0 + 64 + srow)) << 9) + (sqs << 3);

#define STAGE1(t_, bi_) do { \
        const int kc_ = (t_) << 5; \
        gld16(gA0 + kc_, &lds[bi_][0][w * 512]); \
        gld16(gA1 + kc_, &lds[bi_][0][2048 + w * 512]); \
        gld16(gB0 + kc_, &lds[bi_][1][w * 512]); \
        gld16(gB1 + kc_, &lds[bi_][1][2048 + w * 512]); \
    } while (0)

    STAGE1(0, 0); STAGE1(1, 1); STAGE1(2, 2);

    #pragma unroll
    for (int s = 0; s < 16; ++s) {
        if (s < 14)       asm volatile("s_waitcnt vmcnt(8)\n\ts_barrier" ::: "memory");
        else if (s == 14) asm volatile("s_waitcnt vmcnt(4)\n\ts_barrier" ::: "memory");
        else              asm volatile("s_waitcnt vmcnt(0)\n\ts_barrier" ::: "memory");
        if (s < 13) STAGE1(s + 3, (s + 3) & 3);
        const char* A  = (const char*)&lds[s & 3][0][0];
        const char* Bp = (const char*)&lds[s & 3][1][0];
        short8 af[4], bf8[4];
        #pragma unroll
        for (int i = 0; i < 4; ++i) af[i]  = *(const short8*)(A + offA[i]);
        #pragma unroll
        for (int j = 0; j < 4; ++j) bf8[j] = *(const short8*)(Bp + offB[j]);
        __builtin_amdgcn_s_setprio(1);
        #pragma unroll
        for (int i = 0; i < 4; ++i)
            #pragma unroll
            for (int j = 0; j < 4; ++j)
                acc[i][j] = __builtin_amdgcn_mfma_f32_16x16x32_bf16(af[i], bf8[j], acc[i][j], 0, 0, 0);
        __builtin_amdgcn_s_setprio(0);
    }
#undef STAGE1

    // GLU epilogue: fc even = a, fc odd = g (same output col n, same lane)
    ushort* dst = (q0 < 8192) ? yr : pu;
    const int qb = (q0 < 8192) ? q0 : (q0 - 7712);
    const int nb2 = (n0 + wn * 64) >> 1;
    #pragma unroll
    for (int fe = 0; fe < 2; ++fe) {
        const int na = nb2 + fe * 16 + col;
        const float ba = b1[na], bg = b1[512 + na];
        #pragma unroll
        for (int i = 0; i < 4; ++i) {
            const int row = qb + wm * 64 + i * 16 + quad * 4;
            #pragma unroll
            for (int r = 0; r < 4; ++r) {
                float a = acc[i][2 * fe][r] + ba;
                float g = acc[i][2 * fe + 1][r] + bg;
                dst[(((size_t)(row + r)) << 9) + na] = f2bf(a * sigmoidf_(g));
            }
        }
    }
}

// ---- K2: LDS-free streaming depthwise conv + swish -> zb; emits new_cache ----
// REGISTER-LEAN (R3 post-mortem: acc[32]+wreg[31]=63 live floats spilled, VGPR=52,
// VALUBusy 67% of 133us = spill/guard overhead). Now 8 outputs/thread:
// acc[8]+wreg[31]=~47 live -> no spill, 38x8 static-guard unroll.
// utt path: thread=(b,d), 38 coalesced bf16 taps from pu. rc path: 30 pu + 8 yr taps.
__global__ __launch_bounds__(256) void k2_fused(
    const ushort* __restrict__ pu, const ushort* __restrict__ yr,
    const float* __restrict__ wdT, const float* __restrict__ bd,
    ushort* __restrict__ z, float* __restrict__ out)
{
    const int tid = threadIdx.x;
    const int bid = blockIdx.x;
    if (bid < 8192) {
        const int ug = bid & 255, b = (bid >> 8) & 15, dh = bid >> 12;
        const int d = dh * 256 + tid;
        const int u0 = ug * 8;
        float wreg[31];
        #pragma unroll
        for (int k = 0; k < 31; ++k) wreg[k] = wdT[k * 512 + d];
        const float bias = bd[d];
        float acc[8];
        #pragma unroll
        for (int i = 0; i < 8; ++i) acc[i] = bias;
        const ushort* base = pu + (((size_t)u0 * 16 + b) << 9) + d;
        #pragma unroll
        for (int p = 0; p < 38; ++p) {
            float v = bf2f(base[(size_t)p * 8192]);
            #pragma unroll
            for (int i = 0; i < 8; ++i) {
                int k = p - i;
                if (k >= 0 && k < 31) acc[i] = fmaf(wreg[k], v, acc[i]);
            }
        }
        ushort* zp = z + d;
        #pragma unroll
        for (int i = 0; i < 8; ++i) {
            float v = acc[i];
            v = v * sigmoidf_(v - 1.0f);
            zp[((size_t)((R_LEN + u0 + i) * 16 + b)) << 9] = f2bf(v);
        }
        // new_cache: pad frames 2048..2077 = taps p=8..37 of the last u-group (u0=2040)
        if (ug == 255) {
            float* outc = out + 20971520 + ((size_t)b * 512 + d) * 30;
            #pragma unroll
            for (int p = 8; p < 38; ++p)
                outc[p - 8] = bf2f(base[(size_t)p * 8192]);
        }
    } else {
        const int m = bid - 8192;
        const int ci = m & 63, b = (m >> 6) & 15, dh = m >> 10;
        const int d = dh * 256 + tid;
        float wreg[31];
        #pragma unroll
        for (int k = 0; k < 31; ++k) wreg[k] = wdT[k * 512 + d];
        const float bias = bd[d];
        float acc[8];
        #pragma unroll
        for (int j = 0; j < 8; ++j) acc[j] = bias;
        #pragma unroll
        for (int r = 0; r < 38; ++r) {
            const ushort* src = (r < 30)
                ? pu + (((size_t)((32 * ci + 32 + r) * 16 + b)) << 9) + d
                : yr + (((size_t)(((8 * ci) + (r - 30)) * 16 + b)) << 9) + d;
            float v = bf2f(*src);
            #pragma unroll
            for (int j = 0; j < 8; ++j) {
                int k = r - j;
                if (k >= 0 && k < 31) acc[j] = fmaf(wreg[k], v, acc[j]);
            }
        }
        #pragma unroll
        for (int j = 0; j < 8; ++j) {
            float v = acc[j];
            v = v * sigmoidf_(v - 1.0f);
            z[(((size_t)((ci * 8 + j) * 16 + b)) << 9) + d] = f2bf(v);
        }
    }
}

// ---- K3: depth-3 pipelined GEMM (zb @ w2b^T) + bias -> final fp32 ----
__global__ __launch_bounds__(256, 2) void k3_mfma(
    const ushort* __restrict__ zb, const ushort* __restrict__ w2b,
    const float* __restrict__ b2, float* __restrict__ out)
{
    __shared__ __attribute__((aligned(16))) ushort lds[4][2][4096];
    const int tid = threadIdx.x;
    const int w = tid >> 6, lane = tid & 63;
    const int col = lane & 15, quad = lane >> 4;
    const int wm = w >> 1, wn = w & 1;
    const int bid = blockIdx.x;
    const int f = (bid & 7) * 160 + (bid >> 3);
    const int mt = f >> 2, nn = f & 3;
    const int q0 = mt * 128, n0 = nn * 128;

    floatx4 acc[4][4];
    #pragma unroll
    for (int i = 0; i < 4; ++i)
        #pragma unroll
        for (int j = 0; j < 4; ++j) acc[i][j] = 0.f;

    int offA[4], offB[4];
    #pragma unroll
    for (int i = 0; i < 4; ++i) {
        int rA = wm * 64 + i * 16 + col;
        offA[i] = rA * 64 + ((quad ^ ((rA >> 1) & 3)) << 4);
        int rB = wn * 64 + i * 16 + col;
        offB[i] = rB * 64 + ((quad ^ ((rB >> 1) & 3)) << 4);
    }

    const int srow = tid >> 2;
    const int sqs = (tid & 3) ^ ((srow >> 1) & 3);
    const ushort* gA0 = zb  + (((size_t)(q0 + srow))      << 9) + (sqs << 3);
    const ushort* gA1 = zb  + (((size_t)(q0 + 64 + srow)) << 9) + (sqs << 3);
    const ushort* gB0 = w2b + (((size_t)(n0 + srow))      << 9) + (sqs << 3);
    const ushort* gB1 = w2b + (((size_t)(n0 + 64 + srow)) << 9) + (sqs << 3);

#define STAGE3(t_, bi_) do { \
        const int kc_ = (t_) << 5; \
        gld16(gA0 + kc_, &lds[bi_][0][w * 512]); \
        gld16(gA1 + kc_, &lds[bi_][0][2048 + w * 512]); \
        gld16(gB0 + kc_, &lds[bi_][1][w * 512]); \
        gld16(gB1 + kc_, &lds[bi_][1][2048 + w * 512]); \
    } while (0)

    STAGE3(0, 0); STAGE3(1, 1); STAGE3(2, 2);

    #pragma unroll
    for (int s = 0; s < 16; ++s) {
        if (s < 14)       asm volatile("s_waitcnt vmcnt(8)\n\ts_barrier" ::: "memory");
        else if (s == 14) asm volatile("s_waitcnt vmcnt(4)\n\ts_barrier" ::: "memory");
        else              asm volatile("s_waitcnt vmcnt(0)\n\ts_barrier" ::: "memory");
        if (s < 13) STAGE3(s + 3, (s + 3) & 3);
        const char* A  = (const char*)&lds[s & 3][0][0];
        const char* Bp = (const char*)&lds[s & 3][1][0];
        short8 af[4], bf8[4];
        #pragma unroll
        for (int i = 0; i < 4; ++i) af[i]  = *(const short8*)(A + offA[i]);
        #pragma unroll
        for (int j = 0; j < 4; ++j) bf8[j] = *(const short8*)(Bp + offB[j]);
        __builtin_amdgcn_s_setprio(1);
        #pragma unroll
        for (int i = 0; i < 4; ++i)
            #pragma unroll
            for (int j = 0; j < 4; ++j)
                acc[i][j] = __builtin_amdgcn_mfma_f32_16x16x32_bf16(af[i], bf8[j], acc[i][j], 0, 0, 0);
        __builtin_amdgcn_s_setprio(0);
    }
#undef STAGE3

    #pragma unroll
    for (int j = 0; j < 4; ++j) {
        const int n = n0 + wn * 64 + j * 16 + col;
        const float bb = b2[n];
        #pragma unroll
        for (int i = 0; i < 4; ++i) {
            const int qrow = q0 + wm * 64 + i * 16 + quad * 4;
            #pragma unroll
            for (int r = 0; r < 4; ++r) {
                const int q = qrow + r;
                float v = acc[i][j][r] + bb;
                size_t off = (q < 8192) ? (size_t)16777216 + ((size_t)q << 9)
                                        : ((size_t)(q - 8192) << 9);
                out[off + n] = v;
            }
        }
    }
}

extern "C" void kernel_launch(void* const* d_in, const int* in_sizes, int n_in,
                              void* d_out, int out_size, void* d_ws, size_t ws_size,
                              hipStream_t stream)
{
    const float* utt   = (const float*)d_in[0];
    const float* rc    = (const float*)d_in[1];
    const float* cache = (const float*)d_in[2];
    const float* w1    = (const float*)d_in[3];
    const float* b1    = (const float*)d_in[4];
    const float* wd    = (const float*)d_in[5];
    const float* bd    = (const float*)d_in[6];
    const float* w2    = (const float*)d_in[7];
    const float* b2    = (const float*)d_in[8];
    float* out = (float*)d_out;

    ushort* xb  = (ushort*)d_ws;                 // (T,B,D) bf16, rows q=t*16+b
    ushort* zb  = xb  + (size_t)20971520;        // k2 output / k3 input
    ushort* pu  = zb  + (size_t)20971520;        // padded utt: 2078 frames x 16 x 512 bf16
    ushort* yr  = pu  + (size_t)17039360;        // rc GLU rows: 512 frames x 16 x 512 bf16
    ushort* w1b = yr  + (size_t)4194304;         // w1 bf16, 16-row a/g interleaved
    ushort* w2b = w1b + (size_t)524288;
    float*  wdT = (float*)(w2b + (size_t)262144); // [31][512] fp32 transposed dw weights

    k_conv_all<<<dim3(6334), 256, 0, stream>>>(utt, rc, cache, w1, w2, wd, xb, w1b, w2b, pu, wdT);
    k1_mfma   <<<dim3(2560), 256, 0, stream>>>(xb, w1b, b1, yr, pu);
    k2_fused  <<<dim3(10240), 256, 0, stream>>>(pu, yr, wdT, bd, zb, out);
    k3_mfma   <<<dim3(1280), 256, 0, stream>>>(zb, w2b, b2, out);
}